// Round 10
// baseline (2308.548 us; speedup 1.0000x reference)
//
#include <hip/hip_runtime.h>

#define N_PTS  16384
#define B_SZ   8
#define NGROUP 1024
#define KNN_K  32
#define ATTR   7

// d_out layout (floats), reference return order:
// neighborhood (8,1024,32,7), center_idx (8,1024), centroids_attrs (8,1024,7), centroids_coors (8,1024,3)
#define OFF_NB     0
#define OFF_IDX    (B_SZ * NGROUP * KNN_K * ATTR)            // 1835008
#define OFF_CATTR  (OFF_IDX + B_SZ * NGROUP)                 // 1843200
#define OFF_CCOORD (OFF_CATTR + B_SZ * NGROUP * ATTR)        // 1900544

typedef float v2f __attribute__((ext_vector_type(2)));                 // packed-f32 math
typedef float v4f __attribute__((ext_vector_type(4)));                 // LDS 16B tile
typedef float f2u __attribute__((ext_vector_type(2), aligned(4)));     // 4B-aligned vec load

// ---------------------------------------------------------------------------
// DPP 64-lane reductions (VALU-only; no DS-pipe traffic).
// ---------------------------------------------------------------------------
template <int CTRL>
__device__ __forceinline__ float fmax_dpp_step(float x) {
    int d = __builtin_amdgcn_update_dpp(__float_as_int(x), __float_as_int(x),
                                        CTRL, 0xf, 0xf, false);
    return fmaxf(x, __int_as_float(d));
}
template <int CTRL>
__device__ __forceinline__ unsigned umin_dpp_step(unsigned x) {
    unsigned d = (unsigned)__builtin_amdgcn_update_dpp((int)x, (int)x,
                                                       CTRL, 0xf, 0xf, false);
    return x < d ? x : d;
}

__device__ __forceinline__ float wave_max_f32(float x) {
    x = fmax_dpp_step<0x111>(x);   // row_shr:1
    x = fmax_dpp_step<0x112>(x);   // row_shr:2
    x = fmax_dpp_step<0x114>(x);   // row_shr:4
    x = fmax_dpp_step<0x118>(x);   // row_shr:8
    x = fmax_dpp_step<0x142>(x);   // row_bcast15
    x = fmax_dpp_step<0x143>(x);   // row_bcast31 -> lane63 = full-wave max
    return __int_as_float(__builtin_amdgcn_readlane(__float_as_int(x), 63));
}
__device__ __forceinline__ unsigned wave_min_u32(unsigned x) {
    x = umin_dpp_step<0x111>(x);
    x = umin_dpp_step<0x112>(x);
    x = umin_dpp_step<0x114>(x);
    x = umin_dpp_step<0x118>(x);
    x = umin_dpp_step<0x142>(x);
    x = umin_dpp_step<0x143>(x);
    return (unsigned)__builtin_amdgcn_readlane((int)x, 63);
}

// 16-lane u64-key max with carried record index (rows replicate; lane15 of
// each row ends with the row result). row_shr:1/2/4/8, bound_ctrl=false.
template <int CTRL>
__device__ __forceinline__ void kmax_dpp_step(unsigned long long& k, int& r) {
    int lo = __builtin_amdgcn_update_dpp((int)(unsigned)k, (int)(unsigned)k,
                                         CTRL, 0xf, 0xf, false);
    int hi = __builtin_amdgcn_update_dpp((int)(unsigned)(k >> 32),
                                         (int)(unsigned)(k >> 32),
                                         CTRL, 0xf, 0xf, false);
    int rr = __builtin_amdgcn_update_dpp(r, r, CTRL, 0xf, 0xf, false);
    const unsigned long long kk =
        ((unsigned long long)(unsigned)hi << 32) | (unsigned)lo;
    if (kk > k) { k = kk; r = rr; }
}

// ---------------------------------------------------------------------------
// Kernel 0: prep — x2[b][n] = sum_a xyz[b][n][a]^2 (sequential, no FMA) and
// SoA transpose xt[b][a][n] for coalesced KNN reads.
// ---------------------------------------------------------------------------
__global__ void prep_kernel(const float* __restrict__ xyz, float* __restrict__ x2,
                            float* __restrict__ xt) {
#pragma clang fp contract(off)
    int i = blockIdx.x * blockDim.x + threadIdx.x;
    if (i >= B_SZ * N_PTS) return;
    const int b = i >> 14;
    const int p = i & (N_PTS - 1);
    const float* q = xyz + (size_t)i * ATTR;
    f2u a01 = *(const f2u*)q;
    f2u a23 = *(const f2u*)(q + 2);
    f2u a45 = *(const f2u*)(q + 4);
    float a6 = q[6];
    float s = a01.x * a01.x;
    s = s + a01.y * a01.y;
    s = s + a23.x * a23.x;
    s = s + a23.y * a23.y;
    s = s + a45.x * a45.x;
    s = s + a45.y * a45.y;
    s = s + a6 * a6;
    x2[i] = s;
    float* T = xt + (size_t)b * ATTR * N_PTS + p;
    T[0 * N_PTS] = a01.x;
    T[1 * N_PTS] = a01.y;
    T[2 * N_PTS] = a23.x;
    T[3 * N_PTS] = a23.y;
    T[4 * N_PTS] = a45.x;
    T[5 * N_PTS] = a45.y;
    T[6 * N_PTS] = a6;
}

// ---------------------------------------------------------------------------
// Kernel 1: farthest point sampling. One 1024-thread block per batch.
// R1-R9 established: step time = per-CU scan issue (~0.7us, invariant to
// thread count / storage / packing) + ~0.9us serial tail. R10 attacks the
// tail's two big items while keeping selection math bit-identical:
//   * per-wave winner RECORD {u64 key, x,y,z} written by the winning lane
//     (predicated parallel ds_write) replaces the 16-way same-address LDS
//     atomicMax (~300-500 cyc serialization + drain before barrier).
//   * winner coords travel in the record: the candidate's x,y are read from
//     lxy and z selected from registers SPECULATIVELY (hidden under the
//     fmax DPP chain) -> no post-barrier global/L2 winner re-fetch (~250cyc).
//   * post-barrier combine: 16-lane DPP u64-max over records (~100 cyc) +
//     one uniform ds_read_b128.
//   * unique-max fast path (ballot popcount==1) skips the umin DPP chain;
//     the rare exact-tie path keeps it -> identical selections.
// Scan unchanged from R9 (LDS xy v4f tiles + reg z/pd + ra/rb prefetch).
// Math sequence identical (unfused, sequential, contract off). np.argmax
// first-max-wins tie semantics preserved exactly (key = d-bits<<32 |
// 16384-idx; wave umin on exact ties; ascending per-thread scan order).
// ---------------------------------------------------------------------------
#define FOR8(M) M(0) M(1) M(2) M(3) M(4) M(5) M(6) M(7)

#define PT_DECL(J) v2f pz##J, pd##J; v4f ra##J, rb##J;

#define STAGE(J) { \
    const int q = t + (J << 10); \
    const float* r0 = X + (size_t)(q << 1) * ATTR; \
    f2u u0 = *(const f2u*)r0;          float z0 = r0[2]; \
    f2u u1 = *(const f2u*)(r0 + ATTR); float z1 = r0[2 + ATTR]; \
    const v4f xy4 = (v4f){u0.x, u1.x, u0.y, u1.y}; \
    lxy[q] = xy4; \
    ra##J = xy4; \
    rb##J = xy4; \
    pz##J = (v2f){z0, z1}; \
    pd##J = (v2f){1e10f, 1e10f}; }

// one pair-group: prefetch next-step xy into RN, do exact-order math on RC.
#define SCAN1(J, RC, RN) { \
    RN##J = lxy[t + (J << 10)]; \
    const v4f xy = RC##J; \
    v2f dx = (v2f){xy.x, xy.y} - cx2; \
    v2f dy = (v2f){xy.z, xy.w} - cy2; \
    v2f dz = pz##J - cz2; \
    v2f a  = dx * dx; \
    a = a + dy * dy; \
    a = a + dz * dz; \
    v2f nd; \
    nd.x = fminf(pd##J.x, a.x); \
    nd.y = fminf(pd##J.y, a.y); \
    pd##J = nd; \
    if (nd.x > best) { best = nd.x; bidx = (t << 1) + (J << 11); } \
    if (nd.y > best) { best = nd.y; bidx = (t << 1) + (J << 11) + 1; } }

#define FPS_SCAN(RC, RN) \
    SCAN1(0, RC, RN) SCAN1(1, RC, RN) SCAN1(2, RC, RN) SCAN1(3, RC, RN) \
    SCAN1(4, RC, RN) SCAN1(5, RC, RN) SCAN1(6, RC, RN) SCAN1(7, RC, RN)

#define FPS_STEP(SVAL, RC, RN) { \
    const int s_ = (SVAL); \
    const int par = s_ & 1; \
    const v2f cx2 = {cx, cx}, cy2 = {cy, cy}, cz2 = {cz, cz}; \
    float best = -1.0f; \
    int   bidx = 0; \
    FPS_SCAN(RC, RN) \
    /* speculative candidate coords (hidden under the fmax chain) */ \
    const int Jw = (bidx >> 11) & 7; \
    const v4f xyw = lxy[t + (Jw << 10)]; \
    v2f t01 = (Jw & 1) ? pz1 : pz0; \
    v2f t23 = (Jw & 1) ? pz3 : pz2; \
    v2f t45 = (Jw & 1) ? pz5 : pz4; \
    v2f t67 = (Jw & 1) ? pz7 : pz6; \
    v2f u0s = (Jw & 2) ? t23 : t01; \
    v2f u1s = (Jw & 2) ? t67 : t45; \
    v2f vzs = (Jw & 4) ? u1s : u0s; \
    const float zw = (bidx & 1) ? vzs.y : vzs.x; \
    /* wave winner: max distance, tie -> smallest point index (np.argmax) */ \
    const float wm = wave_max_f32(best); \
    const unsigned long long mtie = __ballot(best == wm); \
    int wl; \
    if (__popcll(mtie) == 1) { \
        wl = (int)__ffsll((unsigned long long)mtie) - 1; \
    } else { \
        const unsigned cand = (best == wm) ? (unsigned)bidx : 0xFFFFFFFFu; \
        const unsigned widx = wave_min_u32(cand); \
        wl = (int)__ffsll(__ballot(cand == widx)) - 1; \
    } \
    if (lane == wl) { \
        /* d >= 0 so float bits are order-preserving as u32 */ \
        kbuf[par][w] = ((unsigned long long)__float_as_uint(best) << 32) | \
                       (unsigned)(N_PTS - bidx); \
        const float xw = (bidx & 1) ? xyw.y : xyw.x; \
        const float yw = (bidx & 1) ? xyw.w : xyw.z; \
        cbuf[par][w] = (v4f){xw, yw, zw, 0.0f}; \
    } \
    __syncthreads(); \
    /* combine: 16-lane DPP u64 max over per-wave records (rows replicate) */ \
    unsigned long long bk = kbuf[par][lane & 15]; \
    int rr = lane & 15; \
    kmax_dpp_step<0x111>(bk, rr); \
    kmax_dpp_step<0x112>(bk, rr); \
    kmax_dpp_step<0x114>(bk, rr); \
    kmax_dpp_step<0x118>(bk, rr); \
    const int rwin = __builtin_amdgcn_readlane(rr, 15); \
    const int klo  = __builtin_amdgcn_readlane((int)(unsigned)bk, 15); \
    if (t == 0) sel[s_ + 1] = N_PTS - (int)(unsigned)klo; \
    const v4f wc = cbuf[par][rwin]; \
    cx = wc.x; cy = wc.y; cz = wc.z; }

__global__ __launch_bounds__(1024)
void fps_kernel(const float* __restrict__ xyz, float* __restrict__ out) {
#pragma clang fp contract(off)
    const int b = blockIdx.x;
    const int t = threadIdx.x;
    const int lane = t & 63;
    const int w = t >> 6;                      // wave 0..15
    const float* X = xyz + (size_t)b * N_PTS * ATTR;

    __shared__ v4f lxy[N_PTS / 2];             // {x0,x1,y0,y1} per pair (128 KB)
    __shared__ int sel[NGROUP];                // (4 KB)
    __shared__ unsigned long long kbuf[2][16]; // per-wave winner keys
    __shared__ v4f cbuf[2][16];                // per-wave winner coords

    FOR8(PT_DECL)
    FOR8(STAGE)

    if (t == 0) sel[0] = 0;
    float cx = X[0], cy = X[1], cz = X[2];     // farthest=0 initial centroid
    __syncthreads();

    // steps 0..1021 in role-swapping pairs, then final step 1022.
    for (int s = 0; s < NGROUP - 2; s += 2) {
        FPS_STEP(s,     ra, rb)
        FPS_STEP(s + 1, rb, ra)
    }
    FPS_STEP(NGROUP - 2, ra, rb)
    __syncthreads();

    // outputs: center_idx, centroids_attrs, centroids_coors (1024 threads = 1024 groups)
    {
        const int g = t;
        const int idx = sel[g];
        const float* q = X + (size_t)idx * ATTR;
        float a0 = q[0], a1 = q[1], a2 = q[2], a3 = q[3], a4 = q[4], a5 = q[5], a6 = q[6];
        out[OFF_IDX + b * NGROUP + g] = (float)idx;
        float* ca = out + OFF_CATTR + (size_t)(b * NGROUP + g) * ATTR;
        ca[0] = a0; ca[1] = a1; ca[2] = a2; ca[3] = a3; ca[4] = a4; ca[5] = a5; ca[6] = a6;
        float* cc = out + OFF_CCOORD + (size_t)(b * NGROUP + g) * 3;
        cc[0] = a0; cc[1] = a1; cc[2] = a2;
    }
}

// ---------------------------------------------------------------------------
// distributed top-32 insert (sorted list lives one-slot-per-lane, lanes 0..31)
// ---------------------------------------------------------------------------
__device__ __forceinline__ void topk_insert(float d2, int p, int lane,
                                            float& ld, int& li, float& kd, int& ki) {
    const bool cand = (d2 < kd) || (d2 == kd && p < ki);
    unsigned long long mask = __ballot(cand);
    while (mask) {
        const int l = __ffsll(mask) - 1;
        mask &= mask - 1;
        const float dc = __shfl(d2, l);
        const int   pc = __shfl(p, l);
        if ((dc < kd) || (dc == kd && pc < ki)) {
            const bool before = (ld < dc) || (ld == dc && li < pc);
            const int pos = (int)__popcll(__ballot(before));
            const float sd = __shfl_up(ld, 1);
            const int   si = __shfl_up(li, 1);
            if (lane == pos)      { ld = dc; li = pc; }
            else if (lane > pos)  { ld = sd; li = si; }
            if (lane >= KNN_K)    { ld = __builtin_inff(); li = 0x7fffffff; }
            kd = __shfl(ld, KNN_K - 1);
            ki = __shfl(li, KNN_K - 1);
        }
    }
}

// ---------------------------------------------------------------------------
// Kernel 2: 32-NN in 7-D + gather/recenter. One wave per group.
// SoA path: 7+1 coalesced dword loads per 64-point batch. d2 = (c2+x2)-2*dot.
// ---------------------------------------------------------------------------
__global__ __launch_bounds__(256) void knn_kernel(const float* __restrict__ xyz,
                                                  const float* __restrict__ x2,
                                                  const float* __restrict__ xt,
                                                  float* __restrict__ out) {
#pragma clang fp contract(off)
    const int lane = threadIdx.x & 63;
    const int gg = blockIdx.x * 4 + (threadIdx.x >> 6);   // global group 0..8191
    const int b  = gg >> 10;
    const float* X = xyz + (size_t)b * N_PTS * ATTR;

    const float* C = out + OFF_CATTR + (size_t)gg * ATTR;
    const float c0 = C[0], c1 = C[1], c2a = C[2], c3 = C[3], c4 = C[4], c5 = C[5], c6 = C[6];
    float csq = c0 * c0;
    csq = csq + c1 * c1;
    csq = csq + c2a * c2a;
    csq = csq + c3 * c3;
    csq = csq + c4 * c4;
    csq = csq + c5 * c5;
    csq = csq + c6 * c6;

    float ld = __builtin_inff();
    int   li = 0x7fffffff;
    float kd = __builtin_inff();
    int   ki = 0x7fffffff;

    if (xt != nullptr) {
        const float* T0 = xt + (size_t)b * ATTR * N_PTS;
        const float* T1 = T0 + N_PTS;
        const float* T2 = T1 + N_PTS;
        const float* T3 = T2 + N_PTS;
        const float* T4 = T3 + N_PTS;
        const float* T5 = T4 + N_PTS;
        const float* T6 = T5 + N_PTS;
        const float* XB = x2 + (size_t)b * N_PTS;
        for (int p0 = 0; p0 < N_PTS; p0 += 64) {
            const int p = p0 + lane;
            const float q0 = T0[p], q1 = T1[p], q2 = T2[p], q3 = T3[p];
            const float q4 = T4[p], q5 = T5[p], q6 = T6[p];
            float dot = c0 * q0;
            dot = dot + c1 * q1;
            dot = dot + c2a * q2;
            dot = dot + c3 * q3;
            dot = dot + c4 * q4;
            dot = dot + c5 * q5;
            dot = dot + c6 * q6;
            const float xx = XB[p];
            const float d2 = (csq + xx) - 2.0f * dot;
            topk_insert(d2, p, lane, ld, li, kd, ki);
        }
    } else {
        for (int p0 = 0; p0 < N_PTS; p0 += 64) {
            const int p = p0 + lane;
            const float* q = X + (size_t)p * ATTR;
            float dot = c0 * q[0];
            dot = dot + c1 * q[1];
            dot = dot + c2a * q[2];
            dot = dot + c3 * q[3];
            dot = dot + c4 * q[4];
            dot = dot + c5 * q[5];
            dot = dot + c6 * q[6];
            float xx = q[0] * q[0];
            xx = xx + q[1] * q[1];
            xx = xx + q[2] * q[2];
            xx = xx + q[3] * q[3];
            xx = xx + q[4] * q[4];
            xx = xx + q[5] * q[5];
            xx = xx + q[6] * q[6];
            const float d2 = (csq + xx) - 2.0f * dot;
            topk_insert(d2, p, lane, ld, li, kd, ki);
        }
    }

    // neighborhood output: lane j writes rank-j neighbor (ascending (d2,idx))
    if (lane < KNN_K) {
        const float* q = X + (size_t)li * ATTR;
        float* o = out + OFF_NB + ((size_t)gg * KNN_K + lane) * ATTR;
        o[0] = q[0] - c0;
        o[1] = q[1] - c1;
        o[2] = q[2] - c2a;
        o[3] = q[3];
        o[4] = q[4];
        o[5] = q[5];
        o[6] = q[6];
    }
}

extern "C" void kernel_launch(void* const* d_in, const int* in_sizes, int n_in,
                              void* d_out, int out_size, void* d_ws, size_t ws_size,
                              hipStream_t stream) {
    const float* xyz = (const float*)d_in[0];
    float* out = (float*)d_out;

    const size_t need = (size_t)(B_SZ * N_PTS) * (1 + ATTR) * sizeof(float);  // 4 MiB
    const bool use_ws = ws_size >= need;
    float* x2 = use_ws ? (float*)d_ws : nullptr;
    float* xt = use_ws ? ((float*)d_ws + B_SZ * N_PTS) : nullptr;

    if (use_ws) {
        prep_kernel<<<(B_SZ * N_PTS + 255) / 256, 256, 0, stream>>>(xyz, x2, xt);
    }
    fps_kernel<<<B_SZ, 1024, 0, stream>>>(xyz, out);
    knn_kernel<<<(B_SZ * NGROUP) / 4, 256, 0, stream>>>(xyz, x2, xt, out);
}

// Round 11
// 1947.556 us; speedup vs baseline: 1.1854x; 1.1854x over previous
//
#include <hip/hip_runtime.h>

#define N_PTS  16384
#define B_SZ   8
#define NGROUP 1024
#define KNN_K  32
#define ATTR   7

// d_out layout (floats), reference return order:
// neighborhood (8,1024,32,7), center_idx (8,1024), centroids_attrs (8,1024,7), centroids_coors (8,1024,3)
#define OFF_NB     0
#define OFF_IDX    (B_SZ * NGROUP * KNN_K * ATTR)            // 1835008
#define OFF_CATTR  (OFF_IDX + B_SZ * NGROUP)                 // 1843200
#define OFF_CCOORD (OFF_CATTR + B_SZ * NGROUP * ATTR)        // 1900544

typedef float v2f __attribute__((ext_vector_type(2)));                 // packed-f32 math
typedef float f2u __attribute__((ext_vector_type(2), aligned(4)));     // 4B-aligned vec load

// ---------------------------------------------------------------------------
// DPP 64-lane reductions (VALU-only; no DS-pipe traffic).
// ---------------------------------------------------------------------------
template <int CTRL>
__device__ __forceinline__ float fmax_dpp_step(float x) {
    int d = __builtin_amdgcn_update_dpp(__float_as_int(x), __float_as_int(x),
                                        CTRL, 0xf, 0xf, false);
    return fmaxf(x, __int_as_float(d));
}
template <int CTRL>
__device__ __forceinline__ unsigned umin_dpp_step(unsigned x) {
    unsigned d = (unsigned)__builtin_amdgcn_update_dpp((int)x, (int)x,
                                                       CTRL, 0xf, 0xf, false);
    return x < d ? x : d;
}

__device__ __forceinline__ float wave_max_f32(float x) {
    x = fmax_dpp_step<0x111>(x);   // row_shr:1
    x = fmax_dpp_step<0x112>(x);   // row_shr:2
    x = fmax_dpp_step<0x114>(x);   // row_shr:4
    x = fmax_dpp_step<0x118>(x);   // row_shr:8
    x = fmax_dpp_step<0x142>(x);   // row_bcast15
    x = fmax_dpp_step<0x143>(x);   // row_bcast31 -> lane63 = full-wave max
    return __int_as_float(__builtin_amdgcn_readlane(__float_as_int(x), 63));
}
__device__ __forceinline__ unsigned wave_min_u32(unsigned x) {
    x = umin_dpp_step<0x111>(x);
    x = umin_dpp_step<0x112>(x);
    x = umin_dpp_step<0x114>(x);
    x = umin_dpp_step<0x118>(x);
    x = umin_dpp_step<0x142>(x);
    x = umin_dpp_step<0x143>(x);
    return (unsigned)__builtin_amdgcn_readlane((int)x, 63);
}

// ---------------------------------------------------------------------------
// Kernel 0: prep — x2[b][n] = sum_a xyz[b][n][a]^2 (sequential, no FMA) and
// SoA transpose xt[b][a][n] for coalesced KNN reads.
// ---------------------------------------------------------------------------
__global__ void prep_kernel(const float* __restrict__ xyz, float* __restrict__ x2,
                            float* __restrict__ xt) {
#pragma clang fp contract(off)
    int i = blockIdx.x * blockDim.x + threadIdx.x;
    if (i >= B_SZ * N_PTS) return;
    const int b = i >> 14;
    const int p = i & (N_PTS - 1);
    const float* q = xyz + (size_t)i * ATTR;
    f2u a01 = *(const f2u*)q;
    f2u a23 = *(const f2u*)(q + 2);
    f2u a45 = *(const f2u*)(q + 4);
    float a6 = q[6];
    float s = a01.x * a01.x;
    s = s + a01.y * a01.y;
    s = s + a23.x * a23.x;
    s = s + a23.y * a23.y;
    s = s + a45.x * a45.x;
    s = s + a45.y * a45.y;
    s = s + a6 * a6;
    x2[i] = s;
    float* T = xt + (size_t)b * ATTR * N_PTS + p;
    T[0 * N_PTS] = a01.x;
    T[1 * N_PTS] = a01.y;
    T[2 * N_PTS] = a23.x;
    T[3 * N_PTS] = a23.y;
    T[4 * N_PTS] = a45.x;
    T[5 * N_PTS] = a45.y;
    T[6 * N_PTS] = a6;
}

// ---------------------------------------------------------------------------
// Kernel 1: farthest point sampling — EXACT restore of the round-4 kernel,
// the session's best measured fps (1586 us). 512 threads/block, 32 pts/thread
// as named v2f locals with volatile coordinate loads, waves_per_eu(2,2),
// triple-buffered LDS atomicMax combine, scalar winner fetch.
// R1-R10 established the step is VALU-issue-bound on the 8 active CUs; the
// 512-thread config minimizes per-wave tail replication (8 waves, not 16).
// Math: unfused, sequential, contract off. np.argmax first-max-wins exact.
// ---------------------------------------------------------------------------
#define FOR16(M) M(0) M(1) M(2) M(3) M(4) M(5) M(6) M(7) \
                 M(8) M(9) M(10) M(11) M(12) M(13) M(14) M(15)

#define PT_DECL(J) v2f px##J, py##J, pz##J, pd##J;

#define PT_LOAD(J) { \
    const int p0 = t + ((2 * J) << 9); \
    const float* q0 = X + (size_t)p0 * ATTR; \
    const float* q1 = q0 + (size_t)512 * ATTR; \
    f2u u0 = *(const volatile f2u*)q0; float z0 = ((const volatile float*)q0)[2]; \
    f2u u1 = *(const volatile f2u*)q1; float z1 = ((const volatile float*)q1)[2]; \
    px##J = (v2f){u0.x, u1.x}; \
    py##J = (v2f){u0.y, u1.y}; \
    pz##J = (v2f){z0, z1}; \
    pd##J = (v2f){1e10f, 1e10f}; }

#define PT_STEP(J) { \
    v2f dx = px##J - cx2; \
    v2f dy = py##J - cy2; \
    v2f dz = pz##J - cz2; \
    v2f a  = dx * dx; \
    a = a + dy * dy; \
    a = a + dz * dz; \
    v2f nd; \
    nd.x = fminf(pd##J.x, a.x); \
    nd.y = fminf(pd##J.y, a.y); \
    pd##J = nd; \
    if (nd.x > best) { best = nd.x; bidx = t + ((2 * J) << 9); } \
    if (nd.y > best) { best = nd.y; bidx = t + ((2 * J + 1) << 9); } }

__global__ __launch_bounds__(512)
__attribute__((amdgpu_waves_per_eu(2, 2)))
void fps_kernel(const float* __restrict__ xyz, float* __restrict__ out) {
#pragma clang fp contract(off)
    const int b = blockIdx.x;
    const int t = threadIdx.x;
    const int lane = t & 63;
    const float* X = xyz + (size_t)b * N_PTS * ATTR;

    FOR16(PT_DECL)
    FOR16(PT_LOAD)

    __shared__ unsigned long long slot[3];
    __shared__ int sel[NGROUP];
    if (t == 0) { slot[0] = 0ull; sel[0] = 0; }
    float cx = X[0], cy = X[1], cz = X[2];     // farthest=0 initial centroid
    __syncthreads();

    for (int s = 0; s < NGROUP - 1; ++s) {
        const v2f cx2 = {cx, cx}, cy2 = {cy, cy}, cz2 = {cz, cz};
        float best = -1.0f;
        int   bidx = 0;
        // strict '>' + per-thread ascending scan order == np.argmax semantics.
        FOR16(PT_STEP)
        // wave-level: max distance, then smallest point index among exact ties.
        const float wm = wave_max_f32(best);
        const unsigned cand = (best == wm) ? (unsigned)bidx : 0xFFFFFFFFu;
        const unsigned widx = wave_min_u32(cand);
        if (lane == 0) {
            // d >= 0 so float bits are order-preserving as u32.
            const unsigned long long key =
                ((unsigned long long)__float_as_uint(wm) << 32) |
                (unsigned)(N_PTS - widx);
            atomicMax(&slot[s % 3], key);
        }
        // reset the NEXT step's slot now: reads of this slot happened at step
        // s-2 (before barrier s-1); next step's atomics happen after barrier s.
        if (t == 0) slot[(s + 1) % 3] = 0ull;
        __syncthreads();
        const unsigned long long bk = slot[s % 3];
        const int win = N_PTS - (int)(unsigned)bk;
        const int sbidx = __builtin_amdgcn_readfirstlane(win);
        if (t == 0) sel[s + 1] = sbidx;
        // uniform (SGPR) address -> scalar load of winner coords, L2-hit.
        const float* q = X + (size_t)sbidx * ATTR;
        cx = q[0]; cy = q[1]; cz = q[2];
    }
    __syncthreads();

    // outputs: center_idx, centroids_attrs, centroids_coors (1024 groups, 512 threads)
    for (int g = t; g < NGROUP; g += 512) {
        const int idx = sel[g];
        const float* q = X + (size_t)idx * ATTR;
        float a0 = q[0], a1 = q[1], a2 = q[2], a3 = q[3], a4 = q[4], a5 = q[5], a6 = q[6];
        out[OFF_IDX + b * NGROUP + g] = (float)idx;
        float* ca = out + OFF_CATTR + (size_t)(b * NGROUP + g) * ATTR;
        ca[0] = a0; ca[1] = a1; ca[2] = a2; ca[3] = a3; ca[4] = a4; ca[5] = a5; ca[6] = a6;
        float* cc = out + OFF_CCOORD + (size_t)(b * NGROUP + g) * 3;
        cc[0] = a0; cc[1] = a1; cc[2] = a2;
    }
}

// ---------------------------------------------------------------------------
// distributed top-32 insert (sorted list lives one-slot-per-lane, lanes 0..31)
// ---------------------------------------------------------------------------
__device__ __forceinline__ void topk_insert(float d2, int p, int lane,
                                            float& ld, int& li, float& kd, int& ki) {
    const bool cand = (d2 < kd) || (d2 == kd && p < ki);
    unsigned long long mask = __ballot(cand);
    while (mask) {
        const int l = __ffsll(mask) - 1;
        mask &= mask - 1;
        const float dc = __shfl(d2, l);
        const int   pc = __shfl(p, l);
        if ((dc < kd) || (dc == kd && pc < ki)) {
            const bool before = (ld < dc) || (ld == dc && li < pc);
            const int pos = (int)__popcll(__ballot(before));
            const float sd = __shfl_up(ld, 1);
            const int   si = __shfl_up(li, 1);
            if (lane == pos)      { ld = dc; li = pc; }
            else if (lane > pos)  { ld = sd; li = si; }
            if (lane >= KNN_K)    { ld = __builtin_inff(); li = 0x7fffffff; }
            kd = __shfl(ld, KNN_K - 1);
            ki = __shfl(li, KNN_K - 1);
        }
    }
}

// ---------------------------------------------------------------------------
// Kernel 2: 32-NN in 7-D + gather/recenter. NEW: TWO waves per group — wave
// half=0 scans points [0,8192), half=1 scans [8192,16384); each builds its
// exact top-32; after a barrier wave 0 merges wave 1's 32 candidates via the
// same exact (d2,idx)-ordered insert. d2 bits are wave-independent (same
// formula, same inputs) and A-half indices < B-half indices, so the merged
// list is bit-identical to the single-wave scan. Serial scan per wave halves.
// ---------------------------------------------------------------------------
__global__ __launch_bounds__(256) void knn_kernel(const float* __restrict__ xyz,
                                                  const float* __restrict__ x2,
                                                  const float* __restrict__ xt,
                                                  float* __restrict__ out) {
#pragma clang fp contract(off)
    const int lane = threadIdx.x & 63;
    const int w    = threadIdx.x >> 6;                    // wave 0..3
    const int gib  = w >> 1;                              // group-in-block 0..1
    const int half = w & 1;                               // scan half
    const int gg = blockIdx.x * 2 + gib;                  // global group 0..8191
    const int b  = gg >> 10;
    const float* X = xyz + (size_t)b * N_PTS * ATTR;

    const float* C = out + OFF_CATTR + (size_t)gg * ATTR;
    const float c0 = C[0], c1 = C[1], c2a = C[2], c3 = C[3], c4 = C[4], c5 = C[5], c6 = C[6];
    float csq = c0 * c0;
    csq = csq + c1 * c1;
    csq = csq + c2a * c2a;
    csq = csq + c3 * c3;
    csq = csq + c4 * c4;
    csq = csq + c5 * c5;
    csq = csq + c6 * c6;

    float ld = __builtin_inff();
    int   li = 0x7fffffff;
    float kd = __builtin_inff();
    int   ki = 0x7fffffff;

    const int pbeg = half * (N_PTS / 2);
    const int pend = pbeg + (N_PTS / 2);

    if (xt != nullptr) {
        const float* T0 = xt + (size_t)b * ATTR * N_PTS;
        const float* T1 = T0 + N_PTS;
        const float* T2 = T1 + N_PTS;
        const float* T3 = T2 + N_PTS;
        const float* T4 = T3 + N_PTS;
        const float* T5 = T4 + N_PTS;
        const float* T6 = T5 + N_PTS;
        const float* XB = x2 + (size_t)b * N_PTS;
        for (int p0 = pbeg; p0 < pend; p0 += 64) {
            const int p = p0 + lane;
            const float q0 = T0[p], q1 = T1[p], q2 = T2[p], q3 = T3[p];
            const float q4 = T4[p], q5 = T5[p], q6 = T6[p];
            float dot = c0 * q0;
            dot = dot + c1 * q1;
            dot = dot + c2a * q2;
            dot = dot + c3 * q3;
            dot = dot + c4 * q4;
            dot = dot + c5 * q5;
            dot = dot + c6 * q6;
            const float xx = XB[p];
            const float d2 = (csq + xx) - 2.0f * dot;
            topk_insert(d2, p, lane, ld, li, kd, ki);
        }
    } else {
        for (int p0 = pbeg; p0 < pend; p0 += 64) {
            const int p = p0 + lane;
            const float* q = X + (size_t)p * ATTR;
            float dot = c0 * q[0];
            dot = dot + c1 * q[1];
            dot = dot + c2a * q[2];
            dot = dot + c3 * q[3];
            dot = dot + c4 * q[4];
            dot = dot + c5 * q[5];
            dot = dot + c6 * q[6];
            float xx = q[0] * q[0];
            xx = xx + q[1] * q[1];
            xx = xx + q[2] * q[2];
            xx = xx + q[3] * q[3];
            xx = xx + q[4] * q[4];
            xx = xx + q[5] * q[5];
            xx = xx + q[6] * q[6];
            const float d2 = (csq + xx) - 2.0f * dot;
            topk_insert(d2, p, lane, ld, li, kd, ki);
        }
    }

    // exchange: each wave publishes its sorted top-32; wave half=0 merges.
    __shared__ float smd[2][2][KNN_K];
    __shared__ int   smi[2][2][KNN_K];
    if (lane < KNN_K) {
        smd[gib][half][lane] = ld;
        smi[gib][half][lane] = li;
    }
    __syncthreads();

    if (half == 0) {
        const float dc2 = (lane < KNN_K) ? smd[gib][1][lane] : __builtin_inff();
        const int   pc2 = (lane < KNN_K) ? smi[gib][1][lane] : 0x7fffffff;
        topk_insert(dc2, pc2, lane, ld, li, kd, ki);

        // neighborhood output: lane j writes rank-j neighbor (ascending (d2,idx))
        if (lane < KNN_K) {
            const float* q = X + (size_t)li * ATTR;
            float* o = out + OFF_NB + ((size_t)gg * KNN_K + lane) * ATTR;
            o[0] = q[0] - c0;
            o[1] = q[1] - c1;
            o[2] = q[2] - c2a;
            o[3] = q[3];
            o[4] = q[4];
            o[5] = q[5];
            o[6] = q[6];
        }
    }
}

extern "C" void kernel_launch(void* const* d_in, const int* in_sizes, int n_in,
                              void* d_out, int out_size, void* d_ws, size_t ws_size,
                              hipStream_t stream) {
    const float* xyz = (const float*)d_in[0];
    float* out = (float*)d_out;

    const size_t need = (size_t)(B_SZ * N_PTS) * (1 + ATTR) * sizeof(float);  // 4 MiB
    const bool use_ws = ws_size >= need;
    float* x2 = use_ws ? (float*)d_ws : nullptr;
    float* xt = use_ws ? ((float*)d_ws + B_SZ * N_PTS) : nullptr;

    if (use_ws) {
        prep_kernel<<<(B_SZ * N_PTS + 255) / 256, 256, 0, stream>>>(xyz, x2, xt);
    }
    fps_kernel<<<B_SZ, 512, 0, stream>>>(xyz, out);
    knn_kernel<<<(B_SZ * NGROUP) / 2, 256, 0, stream>>>(xyz, x2, xt, out);
}

// Round 12
// 1905.100 us; speedup vs baseline: 1.2118x; 1.0223x over previous
//
#include <hip/hip_runtime.h>

#define N_PTS  16384
#define B_SZ   8
#define NGROUP 1024
#define KNN_K  32
#define ATTR   7
#define CHUNK  1024

// d_out layout (floats), reference return order:
// neighborhood (8,1024,32,7), center_idx (8,1024), centroids_attrs (8,1024,7), centroids_coors (8,1024,3)
#define OFF_NB     0
#define OFF_IDX    (B_SZ * NGROUP * KNN_K * ATTR)            // 1835008
#define OFF_CATTR  (OFF_IDX + B_SZ * NGROUP)                 // 1843200
#define OFF_CCOORD (OFF_CATTR + B_SZ * NGROUP * ATTR)        // 1900544

typedef float v2f __attribute__((ext_vector_type(2)));                 // packed-f32 math
typedef float f2u __attribute__((ext_vector_type(2), aligned(4)));     // 4B-aligned vec load

// ---------------------------------------------------------------------------
// DPP 64-lane reductions (VALU-only; no DS-pipe traffic).
// ---------------------------------------------------------------------------
template <int CTRL>
__device__ __forceinline__ float fmax_dpp_step(float x) {
    int d = __builtin_amdgcn_update_dpp(__float_as_int(x), __float_as_int(x),
                                        CTRL, 0xf, 0xf, false);
    return fmaxf(x, __int_as_float(d));
}
template <int CTRL>
__device__ __forceinline__ unsigned umin_dpp_step(unsigned x) {
    unsigned d = (unsigned)__builtin_amdgcn_update_dpp((int)x, (int)x,
                                                       CTRL, 0xf, 0xf, false);
    return x < d ? x : d;
}

__device__ __forceinline__ float wave_max_f32(float x) {
    x = fmax_dpp_step<0x111>(x);   // row_shr:1
    x = fmax_dpp_step<0x112>(x);   // row_shr:2
    x = fmax_dpp_step<0x114>(x);   // row_shr:4
    x = fmax_dpp_step<0x118>(x);   // row_shr:8
    x = fmax_dpp_step<0x142>(x);   // row_bcast15
    x = fmax_dpp_step<0x143>(x);   // row_bcast31 -> lane63 = full-wave max
    return __int_as_float(__builtin_amdgcn_readlane(__float_as_int(x), 63));
}
__device__ __forceinline__ unsigned wave_min_u32(unsigned x) {
    x = umin_dpp_step<0x111>(x);
    x = umin_dpp_step<0x112>(x);
    x = umin_dpp_step<0x114>(x);
    x = umin_dpp_step<0x118>(x);
    x = umin_dpp_step<0x142>(x);
    x = umin_dpp_step<0x143>(x);
    return (unsigned)__builtin_amdgcn_readlane((int)x, 63);
}

// ---------------------------------------------------------------------------
// Kernel 0: prep — x2[b][n] = sum_a xyz[b][n][a]^2 (sequential, no FMA) and
// SoA transpose xt[b][a][n] for coalesced KNN reads.
// ---------------------------------------------------------------------------
__global__ void prep_kernel(const float* __restrict__ xyz, float* __restrict__ x2,
                            float* __restrict__ xt) {
#pragma clang fp contract(off)
    int i = blockIdx.x * blockDim.x + threadIdx.x;
    if (i >= B_SZ * N_PTS) return;
    const int b = i >> 14;
    const int p = i & (N_PTS - 1);
    const float* q = xyz + (size_t)i * ATTR;
    f2u a01 = *(const f2u*)q;
    f2u a23 = *(const f2u*)(q + 2);
    f2u a45 = *(const f2u*)(q + 4);
    float a6 = q[6];
    float s = a01.x * a01.x;
    s = s + a01.y * a01.y;
    s = s + a23.x * a23.x;
    s = s + a23.y * a23.y;
    s = s + a45.x * a45.x;
    s = s + a45.y * a45.y;
    s = s + a6 * a6;
    x2[i] = s;
    float* T = xt + (size_t)b * ATTR * N_PTS + p;
    T[0 * N_PTS] = a01.x;
    T[1 * N_PTS] = a01.y;
    T[2 * N_PTS] = a23.x;
    T[3 * N_PTS] = a23.y;
    T[4 * N_PTS] = a45.x;
    T[5 * N_PTS] = a45.y;
    T[6 * N_PTS] = a6;
}

// ---------------------------------------------------------------------------
// Kernel 1: farthest point sampling — UNCHANGED from round 11 (best measured:
// 1552 us). 512 threads/block, 32 pts/thread as named v2f locals with
// volatile coordinate loads, waves_per_eu(2,2), triple-buffered LDS
// atomicMax combine, scalar winner fetch. VALU-issue-bound on 8 CUs; this
// config minimizes per-wave tail replication.
// Math: unfused, sequential, contract off. np.argmax first-max-wins exact.
// ---------------------------------------------------------------------------
#define FOR16(M) M(0) M(1) M(2) M(3) M(4) M(5) M(6) M(7) \
                 M(8) M(9) M(10) M(11) M(12) M(13) M(14) M(15)

#define PT_DECL(J) v2f px##J, py##J, pz##J, pd##J;

#define PT_LOAD(J) { \
    const int p0 = t + ((2 * J) << 9); \
    const float* q0 = X + (size_t)p0 * ATTR; \
    const float* q1 = q0 + (size_t)512 * ATTR; \
    f2u u0 = *(const volatile f2u*)q0; float z0 = ((const volatile float*)q0)[2]; \
    f2u u1 = *(const volatile f2u*)q1; float z1 = ((const volatile float*)q1)[2]; \
    px##J = (v2f){u0.x, u1.x}; \
    py##J = (v2f){u0.y, u1.y}; \
    pz##J = (v2f){z0, z1}; \
    pd##J = (v2f){1e10f, 1e10f}; }

#define PT_STEP(J) { \
    v2f dx = px##J - cx2; \
    v2f dy = py##J - cy2; \
    v2f dz = pz##J - cz2; \
    v2f a  = dx * dx; \
    a = a + dy * dy; \
    a = a + dz * dz; \
    v2f nd; \
    nd.x = fminf(pd##J.x, a.x); \
    nd.y = fminf(pd##J.y, a.y); \
    pd##J = nd; \
    if (nd.x > best) { best = nd.x; bidx = t + ((2 * J) << 9); } \
    if (nd.y > best) { best = nd.y; bidx = t + ((2 * J + 1) << 9); } }

__global__ __launch_bounds__(512)
__attribute__((amdgpu_waves_per_eu(2, 2)))
void fps_kernel(const float* __restrict__ xyz, float* __restrict__ out) {
#pragma clang fp contract(off)
    const int b = blockIdx.x;
    const int t = threadIdx.x;
    const int lane = t & 63;
    const float* X = xyz + (size_t)b * N_PTS * ATTR;

    FOR16(PT_DECL)
    FOR16(PT_LOAD)

    __shared__ unsigned long long slot[3];
    __shared__ int sel[NGROUP];
    if (t == 0) { slot[0] = 0ull; sel[0] = 0; }
    float cx = X[0], cy = X[1], cz = X[2];     // farthest=0 initial centroid
    __syncthreads();

    for (int s = 0; s < NGROUP - 1; ++s) {
        const v2f cx2 = {cx, cx}, cy2 = {cy, cy}, cz2 = {cz, cz};
        float best = -1.0f;
        int   bidx = 0;
        // strict '>' + per-thread ascending scan order == np.argmax semantics.
        FOR16(PT_STEP)
        // wave-level: max distance, then smallest point index among exact ties.
        const float wm = wave_max_f32(best);
        const unsigned cand = (best == wm) ? (unsigned)bidx : 0xFFFFFFFFu;
        const unsigned widx = wave_min_u32(cand);
        if (lane == 0) {
            // d >= 0 so float bits are order-preserving as u32.
            const unsigned long long key =
                ((unsigned long long)__float_as_uint(wm) << 32) |
                (unsigned)(N_PTS - widx);
            atomicMax(&slot[s % 3], key);
        }
        // reset the NEXT step's slot now: reads of this slot happened at step
        // s-2 (before barrier s-1); next step's atomics happen after barrier s.
        if (t == 0) slot[(s + 1) % 3] = 0ull;
        __syncthreads();
        const unsigned long long bk = slot[s % 3];
        const int win = N_PTS - (int)(unsigned)bk;
        const int sbidx = __builtin_amdgcn_readfirstlane(win);
        if (t == 0) sel[s + 1] = sbidx;
        // uniform (SGPR) address -> scalar load of winner coords, L2-hit.
        const float* q = X + (size_t)sbidx * ATTR;
        cx = q[0]; cy = q[1]; cz = q[2];
    }
    __syncthreads();

    // outputs: center_idx, centroids_attrs, centroids_coors (1024 groups, 512 threads)
    for (int g = t; g < NGROUP; g += 512) {
        const int idx = sel[g];
        const float* q = X + (size_t)idx * ATTR;
        float a0 = q[0], a1 = q[1], a2 = q[2], a3 = q[3], a4 = q[4], a5 = q[5], a6 = q[6];
        out[OFF_IDX + b * NGROUP + g] = (float)idx;
        float* ca = out + OFF_CATTR + (size_t)(b * NGROUP + g) * ATTR;
        ca[0] = a0; ca[1] = a1; ca[2] = a2; ca[3] = a3; ca[4] = a4; ca[5] = a5; ca[6] = a6;
        float* cc = out + OFF_CCOORD + (size_t)(b * NGROUP + g) * 3;
        cc[0] = a0; cc[1] = a1; cc[2] = a2;
    }
}

// ---------------------------------------------------------------------------
// distributed top-32 insert (sorted list lives one-slot-per-lane, lanes 0..31)
// ---------------------------------------------------------------------------
__device__ __forceinline__ void topk_insert(float d2, int p, int lane,
                                            float& ld, int& li, float& kd, int& ki) {
    const bool cand = (d2 < kd) || (d2 == kd && p < ki);
    unsigned long long mask = __ballot(cand);
    while (mask) {
        const int l = __ffsll(mask) - 1;
        mask &= mask - 1;
        const float dc = __shfl(d2, l);
        const int   pc = __shfl(p, l);
        if ((dc < kd) || (dc == kd && pc < ki)) {
            const bool before = (ld < dc) || (ld == dc && li < pc);
            const int pos = (int)__popcll(__ballot(before));
            const float sd = __shfl_up(ld, 1);
            const int   si = __shfl_up(li, 1);
            if (lane == pos)      { ld = dc; li = pc; }
            else if (lane > pos)  { ld = sd; li = si; }
            if (lane >= KNN_K)    { ld = __builtin_inff(); li = 0x7fffffff; }
            kd = __shfl(ld, KNN_K - 1);
            ki = __shfl(li, KNN_K - 1);
        }
    }
}

// ---------------------------------------------------------------------------
// Kernel 2: 32-NN in 7-D + gather/recenter. One wave per group; 4 waves per
// block handle 4 groups of the SAME batch (4 | 1024 so no batch straddle).
// R11 lesson: knn is L2/HBM-traffic-bound (4.3 GB reads; 8 batches x 512 KB
// = full per-XCD L2), and at 8192 waves the GPU is already saturated — so
// REUSE, not parallelism: the block LDS-stages the batch's planes in
// 1024-point chunks (8 x 1024 x 4B = 32 KB); all 4 waves scan the chunk
// from LDS (stride-1, conflict-free). Global traffic drops 4x.
// Scan order (chunk-major, 64-stride, ascending) and the d2 arithmetic
// sequence are bit-identical to the pre-split kernel -> bit-exact output.
// ---------------------------------------------------------------------------
__global__ __launch_bounds__(256) void knn_kernel(const float* __restrict__ xyz,
                                                  const float* __restrict__ x2,
                                                  const float* __restrict__ xt,
                                                  float* __restrict__ out) {
#pragma clang fp contract(off)
    const int lane = threadIdx.x & 63;
    const int w    = threadIdx.x >> 6;                    // wave 0..3
    const int gg = blockIdx.x * 4 + w;                    // global group 0..8191
    const int b  = gg >> 10;
    const float* X = xyz + (size_t)b * N_PTS * ATTR;

    const float* C = out + OFF_CATTR + (size_t)gg * ATTR;
    const float c0 = C[0], c1 = C[1], c2a = C[2], c3 = C[3], c4 = C[4], c5 = C[5], c6 = C[6];
    float csq = c0 * c0;
    csq = csq + c1 * c1;
    csq = csq + c2a * c2a;
    csq = csq + c3 * c3;
    csq = csq + c4 * c4;
    csq = csq + c5 * c5;
    csq = csq + c6 * c6;

    float ld = __builtin_inff();
    int   li = 0x7fffffff;
    float kd = __builtin_inff();
    int   ki = 0x7fffffff;

    if (xt != nullptr) {
        __shared__ float sm[8][CHUNK];                    // 7 planes + x2 (32 KB)
        const float* T0 = xt + (size_t)b * ATTR * N_PTS;
        const float* XB = x2 + (size_t)b * N_PTS;
        for (int cb = 0; cb < N_PTS; cb += CHUNK) {
            __syncthreads();                              // prior chunk consumed
            // cooperative stage: coalesced per plane, 256 threads x 4 rounds.
#pragma unroll
            for (int a = 0; a < 7; ++a) {
                const float* Ta = T0 + (size_t)a * N_PTS + cb;
#pragma unroll
                for (int off = 0; off < CHUNK; off += 256)
                    sm[a][off + threadIdx.x] = Ta[off + threadIdx.x];
            }
#pragma unroll
            for (int off = 0; off < CHUNK; off += 256)
                sm[7][off + threadIdx.x] = XB[cb + off + threadIdx.x];
            __syncthreads();
            // each wave scans the chunk from LDS for its own group.
            for (int pp = 0; pp < CHUNK; pp += 64) {
                const int j = pp + lane;
                const int p = cb + j;
                const float q0 = sm[0][j], q1 = sm[1][j], q2 = sm[2][j], q3 = sm[3][j];
                const float q4 = sm[4][j], q5 = sm[5][j], q6 = sm[6][j];
                float dot = c0 * q0;
                dot = dot + c1 * q1;
                dot = dot + c2a * q2;
                dot = dot + c3 * q3;
                dot = dot + c4 * q4;
                dot = dot + c5 * q5;
                dot = dot + c6 * q6;
                const float xx = sm[7][j];
                const float d2 = (csq + xx) - 2.0f * dot;
                topk_insert(d2, p, lane, ld, li, kd, ki);
            }
        }
    } else {
        for (int p0 = 0; p0 < N_PTS; p0 += 64) {
            const int p = p0 + lane;
            const float* q = X + (size_t)p * ATTR;
            float dot = c0 * q[0];
            dot = dot + c1 * q[1];
            dot = dot + c2a * q[2];
            dot = dot + c3 * q[3];
            dot = dot + c4 * q[4];
            dot = dot + c5 * q[5];
            dot = dot + c6 * q[6];
            float xx = q[0] * q[0];
            xx = xx + q[1] * q[1];
            xx = xx + q[2] * q[2];
            xx = xx + q[3] * q[3];
            xx = xx + q[4] * q[4];
            xx = xx + q[5] * q[5];
            xx = xx + q[6] * q[6];
            const float d2 = (csq + xx) - 2.0f * dot;
            topk_insert(d2, p, lane, ld, li, kd, ki);
        }
    }

    // neighborhood output: lane j writes rank-j neighbor (ascending (d2,idx))
    if (lane < KNN_K) {
        const float* q = X + (size_t)li * ATTR;
        float* o = out + OFF_NB + ((size_t)gg * KNN_K + lane) * ATTR;
        o[0] = q[0] - c0;
        o[1] = q[1] - c1;
        o[2] = q[2] - c2a;
        o[3] = q[3];
        o[4] = q[4];
        o[5] = q[5];
        o[6] = q[6];
    }
}

extern "C" void kernel_launch(void* const* d_in, const int* in_sizes, int n_in,
                              void* d_out, int out_size, void* d_ws, size_t ws_size,
                              hipStream_t stream) {
    const float* xyz = (const float*)d_in[0];
    float* out = (float*)d_out;

    const size_t need = (size_t)(B_SZ * N_PTS) * (1 + ATTR) * sizeof(float);  // 4 MiB
    const bool use_ws = ws_size >= need;
    float* x2 = use_ws ? (float*)d_ws : nullptr;
    float* xt = use_ws ? ((float*)d_ws + B_SZ * N_PTS) : nullptr;

    if (use_ws) {
        prep_kernel<<<(B_SZ * N_PTS + 255) / 256, 256, 0, stream>>>(xyz, x2, xt);
    }
    fps_kernel<<<B_SZ, 512, 0, stream>>>(xyz, out);
    knn_kernel<<<(B_SZ * NGROUP) / 4, 256, 0, stream>>>(xyz, x2, xt, out);
}

// Round 13
// 1874.735 us; speedup vs baseline: 1.2314x; 1.0162x over previous
//
#include <hip/hip_runtime.h>

#define N_PTS  16384
#define B_SZ   8
#define NGROUP 1024
#define KNN_K  32
#define ATTR   7

// d_out layout (floats), reference return order:
// neighborhood (8,1024,32,7), center_idx (8,1024), centroids_attrs (8,1024,7), centroids_coors (8,1024,3)
#define OFF_NB     0
#define OFF_IDX    (B_SZ * NGROUP * KNN_K * ATTR)            // 1835008
#define OFF_CATTR  (OFF_IDX + B_SZ * NGROUP)                 // 1843200
#define OFF_CCOORD (OFF_CATTR + B_SZ * NGROUP * ATTR)        // 1900544

typedef float v2f __attribute__((ext_vector_type(2)));                 // packed-f32 math
typedef float f2u __attribute__((ext_vector_type(2), aligned(4)));     // 4B-aligned vec load

// ---------------------------------------------------------------------------
// DPP 64-lane reductions (VALU-only; no DS-pipe traffic).
// ---------------------------------------------------------------------------
template <int CTRL>
__device__ __forceinline__ float fmax_dpp_step(float x) {
    int d = __builtin_amdgcn_update_dpp(__float_as_int(x), __float_as_int(x),
                                        CTRL, 0xf, 0xf, false);
    return fmaxf(x, __int_as_float(d));
}
template <int CTRL>
__device__ __forceinline__ unsigned umin_dpp_step(unsigned x) {
    unsigned d = (unsigned)__builtin_amdgcn_update_dpp((int)x, (int)x,
                                                       CTRL, 0xf, 0xf, false);
    return x < d ? x : d;
}

__device__ __forceinline__ float wave_max_f32(float x) {
    x = fmax_dpp_step<0x111>(x);   // row_shr:1
    x = fmax_dpp_step<0x112>(x);   // row_shr:2
    x = fmax_dpp_step<0x114>(x);   // row_shr:4
    x = fmax_dpp_step<0x118>(x);   // row_shr:8
    x = fmax_dpp_step<0x142>(x);   // row_bcast15
    x = fmax_dpp_step<0x143>(x);   // row_bcast31 -> lane63 = full-wave max
    return __int_as_float(__builtin_amdgcn_readlane(__float_as_int(x), 63));
}
__device__ __forceinline__ unsigned wave_min_u32(unsigned x) {
    x = umin_dpp_step<0x111>(x);
    x = umin_dpp_step<0x112>(x);
    x = umin_dpp_step<0x114>(x);
    x = umin_dpp_step<0x118>(x);
    x = umin_dpp_step<0x142>(x);
    x = umin_dpp_step<0x143>(x);
    return (unsigned)__builtin_amdgcn_readlane((int)x, 63);
}

// ---------------------------------------------------------------------------
// Kernel 0: prep — x2[b][n] = sum_a xyz[b][n][a]^2 (sequential, no FMA) and
// SoA transpose xt[b][a][n] for coalesced KNN reads.
// ---------------------------------------------------------------------------
__global__ void prep_kernel(const float* __restrict__ xyz, float* __restrict__ x2,
                            float* __restrict__ xt) {
#pragma clang fp contract(off)
    int i = blockIdx.x * blockDim.x + threadIdx.x;
    if (i >= B_SZ * N_PTS) return;
    const int b = i >> 14;
    const int p = i & (N_PTS - 1);
    const float* q = xyz + (size_t)i * ATTR;
    f2u a01 = *(const f2u*)q;
    f2u a23 = *(const f2u*)(q + 2);
    f2u a45 = *(const f2u*)(q + 4);
    float a6 = q[6];
    float s = a01.x * a01.x;
    s = s + a01.y * a01.y;
    s = s + a23.x * a23.x;
    s = s + a23.y * a23.y;
    s = s + a45.x * a45.x;
    s = s + a45.y * a45.y;
    s = s + a6 * a6;
    x2[i] = s;
    float* T = xt + (size_t)b * ATTR * N_PTS + p;
    T[0 * N_PTS] = a01.x;
    T[1 * N_PTS] = a01.y;
    T[2 * N_PTS] = a23.x;
    T[3 * N_PTS] = a23.y;
    T[4 * N_PTS] = a45.x;
    T[5 * N_PTS] = a45.y;
    T[6 * N_PTS] = a6;
}

// ---------------------------------------------------------------------------
// Kernel 1: farthest point sampling — UNCHANGED (best measured: 1550 us,
// stable across 3 rounds). 512 threads/block, 32 pts/thread as named v2f
// locals with volatile coordinate loads, waves_per_eu(2,2), triple-buffered
// LDS atomicMax combine, scalar winner fetch. VALU-issue-bound on 8 CUs.
// Math: unfused, sequential, contract off. np.argmax first-max-wins exact.
// ---------------------------------------------------------------------------
#define FOR16(M) M(0) M(1) M(2) M(3) M(4) M(5) M(6) M(7) \
                 M(8) M(9) M(10) M(11) M(12) M(13) M(14) M(15)

#define PT_DECL(J) v2f px##J, py##J, pz##J, pd##J;

#define PT_LOAD(J) { \
    const int p0 = t + ((2 * J) << 9); \
    const float* q0 = X + (size_t)p0 * ATTR; \
    const float* q1 = q0 + (size_t)512 * ATTR; \
    f2u u0 = *(const volatile f2u*)q0; float z0 = ((const volatile float*)q0)[2]; \
    f2u u1 = *(const volatile f2u*)q1; float z1 = ((const volatile float*)q1)[2]; \
    px##J = (v2f){u0.x, u1.x}; \
    py##J = (v2f){u0.y, u1.y}; \
    pz##J = (v2f){z0, z1}; \
    pd##J = (v2f){1e10f, 1e10f}; }

#define PT_STEP(J) { \
    v2f dx = px##J - cx2; \
    v2f dy = py##J - cy2; \
    v2f dz = pz##J - cz2; \
    v2f a  = dx * dx; \
    a = a + dy * dy; \
    a = a + dz * dz; \
    v2f nd; \
    nd.x = fminf(pd##J.x, a.x); \
    nd.y = fminf(pd##J.y, a.y); \
    pd##J = nd; \
    if (nd.x > best) { best = nd.x; bidx = t + ((2 * J) << 9); } \
    if (nd.y > best) { best = nd.y; bidx = t + ((2 * J + 1) << 9); } }

__global__ __launch_bounds__(512)
__attribute__((amdgpu_waves_per_eu(2, 2)))
void fps_kernel(const float* __restrict__ xyz, float* __restrict__ out) {
#pragma clang fp contract(off)
    const int b = blockIdx.x;
    const int t = threadIdx.x;
    const int lane = t & 63;
    const float* X = xyz + (size_t)b * N_PTS * ATTR;

    FOR16(PT_DECL)
    FOR16(PT_LOAD)

    __shared__ unsigned long long slot[3];
    __shared__ int sel[NGROUP];
    if (t == 0) { slot[0] = 0ull; sel[0] = 0; }
    float cx = X[0], cy = X[1], cz = X[2];     // farthest=0 initial centroid
    __syncthreads();

    for (int s = 0; s < NGROUP - 1; ++s) {
        const v2f cx2 = {cx, cx}, cy2 = {cy, cy}, cz2 = {cz, cz};
        float best = -1.0f;
        int   bidx = 0;
        // strict '>' + per-thread ascending scan order == np.argmax semantics.
        FOR16(PT_STEP)
        // wave-level: max distance, then smallest point index among exact ties.
        const float wm = wave_max_f32(best);
        const unsigned cand = (best == wm) ? (unsigned)bidx : 0xFFFFFFFFu;
        const unsigned widx = wave_min_u32(cand);
        if (lane == 0) {
            // d >= 0 so float bits are order-preserving as u32.
            const unsigned long long key =
                ((unsigned long long)__float_as_uint(wm) << 32) |
                (unsigned)(N_PTS - widx);
            atomicMax(&slot[s % 3], key);
        }
        // reset the NEXT step's slot now: reads of this slot happened at step
        // s-2 (before barrier s-1); next step's atomics happen after barrier s.
        if (t == 0) slot[(s + 1) % 3] = 0ull;
        __syncthreads();
        const unsigned long long bk = slot[s % 3];
        const int win = N_PTS - (int)(unsigned)bk;
        const int sbidx = __builtin_amdgcn_readfirstlane(win);
        if (t == 0) sel[s + 1] = sbidx;
        // uniform (SGPR) address -> scalar load of winner coords, L2-hit.
        const float* q = X + (size_t)sbidx * ATTR;
        cx = q[0]; cy = q[1]; cz = q[2];
    }
    __syncthreads();

    // outputs: center_idx, centroids_attrs, centroids_coors (1024 groups, 512 threads)
    for (int g = t; g < NGROUP; g += 512) {
        const int idx = sel[g];
        const float* q = X + (size_t)idx * ATTR;
        float a0 = q[0], a1 = q[1], a2 = q[2], a3 = q[3], a4 = q[4], a5 = q[5], a6 = q[6];
        out[OFF_IDX + b * NGROUP + g] = (float)idx;
        float* ca = out + OFF_CATTR + (size_t)(b * NGROUP + g) * ATTR;
        ca[0] = a0; ca[1] = a1; ca[2] = a2; ca[3] = a3; ca[4] = a4; ca[5] = a5; ca[6] = a6;
        float* cc = out + OFF_CCOORD + (size_t)(b * NGROUP + g) * 3;
        cc[0] = a0; cc[1] = a1; cc[2] = a2;
    }
}

// ---------------------------------------------------------------------------
// distributed top-32 insert (sorted list lives one-slot-per-lane, lanes 0..31)
// ---------------------------------------------------------------------------
__device__ __forceinline__ void topk_insert(float d2, int p, int lane,
                                            float& ld, int& li, float& kd, int& ki) {
    const bool cand = (d2 < kd) || (d2 == kd && p < ki);
    unsigned long long mask = __ballot(cand);
    while (mask) {
        const int l = __ffsll(mask) - 1;
        mask &= mask - 1;
        const float dc = __shfl(d2, l);
        const int   pc = __shfl(p, l);
        if ((dc < kd) || (dc == kd && pc < ki)) {
            const bool before = (ld < dc) || (ld == dc && li < pc);
            const int pos = (int)__popcll(__ballot(before));
            const float sd = __shfl_up(ld, 1);
            const int   si = __shfl_up(li, 1);
            if (lane == pos)      { ld = dc; li = pc; }
            else if (lane > pos)  { ld = sd; li = si; }
            if (lane >= KNN_K)    { ld = __builtin_inff(); li = 0x7fffffff; }
            kd = __shfl(ld, KNN_K - 1);
            ki = __shfl(li, KNN_K - 1);
        }
    }
}

// ---------------------------------------------------------------------------
// Kernel 2: 32-NN in 7-D + gather/recenter — REVERTED to the R1-R9 version
// (best measured: rest ~324-326 us). One wave per group, 4 groups per block,
// global SoA reads (7+1 coalesced dwords per 64-point batch). R11's 2-wave
// split (+70 us) and R12's LDS chunk staging (+30 us) both regressed: knn is
// L2-supplied (~15 TB/s effective) on a saturated grid; reshuffles only
// added barriers/merge overhead. d2 = (c2+x2)-2*dot, sums sequential,
// unfused, contract off.
// ---------------------------------------------------------------------------
__global__ __launch_bounds__(256) void knn_kernel(const float* __restrict__ xyz,
                                                  const float* __restrict__ x2,
                                                  const float* __restrict__ xt,
                                                  float* __restrict__ out) {
#pragma clang fp contract(off)
    const int lane = threadIdx.x & 63;
    const int gg = blockIdx.x * 4 + (threadIdx.x >> 6);   // global group 0..8191
    const int b  = gg >> 10;
    const float* X = xyz + (size_t)b * N_PTS * ATTR;

    const float* C = out + OFF_CATTR + (size_t)gg * ATTR;
    const float c0 = C[0], c1 = C[1], c2a = C[2], c3 = C[3], c4 = C[4], c5 = C[5], c6 = C[6];
    float csq = c0 * c0;
    csq = csq + c1 * c1;
    csq = csq + c2a * c2a;
    csq = csq + c3 * c3;
    csq = csq + c4 * c4;
    csq = csq + c5 * c5;
    csq = csq + c6 * c6;

    float ld = __builtin_inff();
    int   li = 0x7fffffff;
    float kd = __builtin_inff();
    int   ki = 0x7fffffff;

    if (xt != nullptr) {
        const float* T0 = xt + (size_t)b * ATTR * N_PTS;
        const float* T1 = T0 + N_PTS;
        const float* T2 = T1 + N_PTS;
        const float* T3 = T2 + N_PTS;
        const float* T4 = T3 + N_PTS;
        const float* T5 = T4 + N_PTS;
        const float* T6 = T5 + N_PTS;
        const float* XB = x2 + (size_t)b * N_PTS;
        for (int p0 = 0; p0 < N_PTS; p0 += 64) {
            const int p = p0 + lane;
            const float q0 = T0[p], q1 = T1[p], q2 = T2[p], q3 = T3[p];
            const float q4 = T4[p], q5 = T5[p], q6 = T6[p];
            float dot = c0 * q0;
            dot = dot + c1 * q1;
            dot = dot + c2a * q2;
            dot = dot + c3 * q3;
            dot = dot + c4 * q4;
            dot = dot + c5 * q5;
            dot = dot + c6 * q6;
            const float xx = XB[p];
            const float d2 = (csq + xx) - 2.0f * dot;
            topk_insert(d2, p, lane, ld, li, kd, ki);
        }
    } else {
        for (int p0 = 0; p0 < N_PTS; p0 += 64) {
            const int p = p0 + lane;
            const float* q = X + (size_t)p * ATTR;
            float dot = c0 * q[0];
            dot = dot + c1 * q[1];
            dot = dot + c2a * q[2];
            dot = dot + c3 * q[3];
            dot = dot + c4 * q[4];
            dot = dot + c5 * q[5];
            dot = dot + c6 * q[6];
            float xx = q[0] * q[0];
            xx = xx + q[1] * q[1];
            xx = xx + q[2] * q[2];
            xx = xx + q[3] * q[3];
            xx = xx + q[4] * q[4];
            xx = xx + q[5] * q[5];
            xx = xx + q[6] * q[6];
            const float d2 = (csq + xx) - 2.0f * dot;
            topk_insert(d2, p, lane, ld, li, kd, ki);
        }
    }

    // neighborhood output: lane j writes rank-j neighbor (ascending (d2,idx))
    if (lane < KNN_K) {
        const float* q = X + (size_t)li * ATTR;
        float* o = out + OFF_NB + ((size_t)gg * KNN_K + lane) * ATTR;
        o[0] = q[0] - c0;
        o[1] = q[1] - c1;
        o[2] = q[2] - c2a;
        o[3] = q[3];
        o[4] = q[4];
        o[5] = q[5];
        o[6] = q[6];
    }
}

extern "C" void kernel_launch(void* const* d_in, const int* in_sizes, int n_in,
                              void* d_out, int out_size, void* d_ws, size_t ws_size,
                              hipStream_t stream) {
    const float* xyz = (const float*)d_in[0];
    float* out = (float*)d_out;

    const size_t need = (size_t)(B_SZ * N_PTS) * (1 + ATTR) * sizeof(float);  // 4 MiB
    const bool use_ws = ws_size >= need;
    float* x2 = use_ws ? (float*)d_ws : nullptr;
    float* xt = use_ws ? ((float*)d_ws + B_SZ * N_PTS) : nullptr;

    if (use_ws) {
        prep_kernel<<<(B_SZ * N_PTS + 255) / 256, 256, 0, stream>>>(xyz, x2, xt);
    }
    fps_kernel<<<B_SZ, 512, 0, stream>>>(xyz, out);
    knn_kernel<<<(B_SZ * NGROUP) / 4, 256, 0, stream>>>(xyz, x2, xt, out);
}